// Round 1
// baseline (475.674 us; speedup 1.0000x reference)
//
#include <hip/hip_runtime.h>
#include <stdint.h>
#include <stddef.h>

typedef __attribute__((ext_vector_type(8))) short short8;
typedef __attribute__((ext_vector_type(4))) short short4v;
typedef __attribute__((ext_vector_type(4))) float floatx4;

#define MFMA_BF16(A, B, C) __builtin_amdgcn_mfma_f32_16x16x32_bf16((A), (B), (C), 0, 0, 0)

static constexpr int NB   = 32768;
static constexpr int LV   = 1024;
static constexpr int HIDV = 256;
static constexpr int OUTV = 1024;
static constexpr int MSUM = 341;     // L/3
static constexpr int SPAD = 384;     // padded summed width
static constexpr int K1   = 1365;
static constexpr int K1P  = 1408;    // 22 * 64
static constexpr size_t HOFF = (size_t)NB * OUTV;  // fund comes first in d_out

__device__ __forceinline__ short f2bf(float f) {
  union { float f; uint32_t u; } c; c.f = f;
  uint32_t u = c.u;
  u += 0x7fffu + ((u >> 16) & 1u);   // RNE to bf16
  return (short)(u >> 16);
}

// ---- weight conversion: W1 (256 x 1365 fp32) -> bf16 padded to 256 x 1408 ----
__global__ __launch_bounds__(256) void wconv1(const float* __restrict__ W1,
                                              short* __restrict__ w1bf) {
  int idx = blockIdx.x * 256 + threadIdx.x;   // grid = 1408 -> covers 256*1408
  int n = idx / K1P;
  int k = idx - n * K1P;
  float v = (k < K1) ? W1[n * K1 + k] : 0.f;
  w1bf[idx] = f2bf(v);
}

// ---- W2 (1024 x 256 fp32) -> bf16, same layout ----
__global__ __launch_bounds__(256) void wconv2(const float* __restrict__ W2,
                                              short* __restrict__ w2bf) {
  int idx = blockIdx.x * 256 + threadIdx.x;   // grid = 1024
  w2bf[idx] = f2bf(W2[idx]);
}

// ---- summed prep: sbf[b][j] = h[j] + (h[2j]+h[2j+1])/2 + (h[3j]+h[3j+1]+h[3j+2])/3 ----
__global__ __launch_bounds__(256) void prep_summed(const float* __restrict__ x,
                                                   short* __restrict__ sbf) {
  __shared__ __align__(16) float hs[8][1032];
  const int t = threadIdx.x;
  const int row0 = blockIdx.x * 8;
  #pragma unroll
  for (int i = 0; i < 8; ++i) {
    const float4 v = *reinterpret_cast<const float4*>(x + (size_t)(row0 + i) * LV + t * 4);
    *reinterpret_cast<float4*>(&hs[i][t * 4]) = v;
  }
  __syncthreads();
  #pragma unroll
  for (int i = 0; i < 12; ++i) {   // 8 rows * 384 cols / 256 threads
    int e = i * 256 + t;
    int r = e / SPAD;
    int j = e - r * SPAD;
    float val = 0.f;
    if (j < MSUM) {
      val = hs[r][j]
          + 0.5f * (hs[r][2 * j] + hs[r][2 * j + 1])
          + (1.f / 3.f) * (hs[r][3 * j] + hs[r][3 * j + 1] + hs[r][3 * j + 2]);
    }
    sbf[(size_t)(row0 + r) * SPAD + j] = f2bf(val);
  }
}

// ---- fused GEMM1 (relu) + GEMM2 + h-copy ----
// block: 512 threads = 8 waves; M-tile = 64 rows; wave w owns n-slice [w*32, w*32+32)
// of GEMM1 and o-slices [half*512 + w*64, +64) of GEMM2 (each W row read once/block).
__global__ __launch_bounds__(512, 2) void gemm_fused(
    const float* __restrict__ x, const short* __restrict__ sbf,
    const short* __restrict__ w1bf, const short* __restrict__ w2bf,
    const float* __restrict__ b1, const float* __restrict__ b2,
    float* __restrict__ out) {
  // row stride 72 elems (144 B): stride/16B = 9 (odd) -> balanced LDS bank groups for b128
  __shared__ __align__(16) short Abuf[2][64 * 72];
  // row stride 264 elems (528 B): /16B = 33 (odd) -> balanced
  __shared__ __align__(16) short Hbuf[64 * 264];

  const int tid  = threadIdx.x;
  const int wave = tid >> 6;
  const int lane = tid & 63;
  const int l15  = lane & 15;
  const int quad = lane >> 4;
  const int row0 = blockIdx.x * 64;

  const int srow = tid >> 3;   // staging: 0..63
  const int sseg = tid & 7;    // staging: 0..7

  float4 xa, xb;               // x-chunk prefetch (8 fp32)
  short8 sa;                   // summed-chunk prefetch (8 bf16)
  const floatx4 fzero = {0.f, 0.f, 0.f, 0.f};

  auto loadA = [&](int ck) {
    if (ck < 16) {
      const float4* xr = reinterpret_cast<const float4*>(x + (size_t)(row0 + srow) * LV + ck * 64);
      xa = xr[sseg];
      xb = xr[sseg + 8];
    } else {
      sa = *reinterpret_cast<const short8*>(sbf + (size_t)(row0 + srow) * SPAD + (ck - 16) * 64 + sseg * 8);
    }
  };
  auto writeA = [&](int buf, int ck) {
    short* dst = &Abuf[buf][srow * 72];
    if (ck < 16) {
      short4v p0, p1;
      p0.x = f2bf(xa.x); p0.y = f2bf(xa.y); p0.z = f2bf(xa.z); p0.w = f2bf(xa.w);
      p1.x = f2bf(xb.x); p1.y = f2bf(xb.y); p1.z = f2bf(xb.z); p1.w = f2bf(xb.w);
      *reinterpret_cast<short4v*>(dst + sseg * 4)      = p0;
      *reinterpret_cast<short4v*>(dst + sseg * 4 + 32) = p1;
      // fused h-copy (each x element staged exactly once)
      float4* hdst = reinterpret_cast<float4*>(out + HOFF + (size_t)(row0 + srow) * LV + ck * 64);
      hdst[sseg]     = xa;
      hdst[sseg + 8] = xb;
    } else {
      *reinterpret_cast<short8*>(dst + sseg * 8) = sa;
    }
  };

  short8 Breg[2][2];
  auto loadB1 = [&](int ck) {
    const int c0 = ck * 64;
    #pragma unroll
    for (int ks = 0; ks < 2; ++ks)
      #pragma unroll
      for (int ns = 0; ns < 2; ++ns)
        Breg[ks][ns] = *reinterpret_cast<const short8*>(
            w1bf + (size_t)(wave * 32 + ns * 16 + l15) * K1P + c0 + ks * 32 + quad * 8);
  };

  floatx4 acc1[4][2];
  #pragma unroll
  for (int ms = 0; ms < 4; ++ms)
    #pragma unroll
    for (int ns = 0; ns < 2; ++ns)
      acc1[ms][ns] = fzero;

  loadA(0);
  loadB1(0);

  // K-loop: 22 chunks of BK=64, double-buffered LDS, one barrier per chunk
  #pragma unroll 1
  for (int ck = 0; ck < 22; ++ck) {
    const int buf = ck & 1;
    writeA(buf, ck);
    if (ck < 21) loadA(ck + 1);
    __syncthreads();
    #pragma unroll
    for (int ks = 0; ks < 2; ++ks) {
      short8 afr[4];
      #pragma unroll
      for (int ms = 0; ms < 4; ++ms)
        afr[ms] = *reinterpret_cast<const short8*>(&Abuf[buf][(ms * 16 + l15) * 72 + ks * 32 + quad * 8]);
      #pragma unroll
      for (int ms = 0; ms < 4; ++ms)
        #pragma unroll
        for (int ns = 0; ns < 2; ++ns)
          acc1[ms][ns] = MFMA_BF16(afr[ms], Breg[ks][ns], acc1[ms][ns]);
    }
    if (ck < 21) loadB1(ck + 1);
  }

  // GEMM1 epilogue: bias + relu -> bf16 Hbuf (C-layout: row = quad*4+r, col = l15)
  #pragma unroll
  for (int ms = 0; ms < 4; ++ms) {
    #pragma unroll
    for (int ns = 0; ns < 2; ++ns) {
      const int n = wave * 32 + ns * 16 + l15;
      const float bias = b1[n];
      #pragma unroll
      for (int r = 0; r < 4; ++r) {
        const int m = ms * 16 + quad * 4 + r;
        float v = acc1[ms][ns][r] + bias;
        Hbuf[m * 264 + n] = f2bf(v > 0.f ? v : 0.f);
      }
    }
  }
  __syncthreads();

  // GEMM2: K=256 from Hbuf, two sequential N-halves of 512 (acc register cap)
  short8 B2[4];
  auto loadB2 = [&](int half, int kc) {
    #pragma unroll
    for (int ns = 0; ns < 4; ++ns)
      B2[ns] = *reinterpret_cast<const short8*>(
          w2bf + (size_t)(half * 512 + wave * 64 + ns * 16 + l15) * HIDV + kc * 32 + quad * 8);
  };

  #pragma unroll 1
  for (int half = 0; half < 2; ++half) {
    floatx4 acc2[4][4];
    #pragma unroll
    for (int ms = 0; ms < 4; ++ms)
      #pragma unroll
      for (int ns = 0; ns < 4; ++ns)
        acc2[ms][ns] = fzero;
    loadB2(half, 0);
    #pragma unroll 1
    for (int kc = 0; kc < 8; ++kc) {
      short8 afr[4];
      #pragma unroll
      for (int ms = 0; ms < 4; ++ms)
        afr[ms] = *reinterpret_cast<const short8*>(&Hbuf[(ms * 16 + l15) * 264 + kc * 32 + quad * 8]);
      short8 bc[4];
      #pragma unroll
      for (int ns = 0; ns < 4; ++ns) bc[ns] = B2[ns];
      if (kc < 7) loadB2(half, kc + 1);
      #pragma unroll
      for (int ms = 0; ms < 4; ++ms)
        #pragma unroll
        for (int ns = 0; ns < 4; ++ns)
          acc2[ms][ns] = MFMA_BF16(afr[ms], bc[ns], acc2[ms][ns]);
    }
    #pragma unroll
    for (int ms = 0; ms < 4; ++ms) {
      #pragma unroll
      for (int ns = 0; ns < 4; ++ns) {
        const int o = half * 512 + wave * 64 + ns * 16 + l15;
        const float bias = b2[o];
        #pragma unroll
        for (int r = 0; r < 4; ++r) {
          const int m = ms * 16 + quad * 4 + r;
          out[(size_t)(row0 + m) * OUTV + o] = acc2[ms][ns][r] + bias;
        }
      }
    }
  }
}

extern "C" void kernel_launch(void* const* d_in, const int* in_sizes, int n_in,
                              void* d_out, int out_size, void* d_ws, size_t ws_size,
                              hipStream_t stream) {
  const float* x  = (const float*)d_in[0];
  const float* W1 = (const float*)d_in[1];
  const float* b1 = (const float*)d_in[2];
  const float* W2 = (const float*)d_in[3];
  const float* b2 = (const float*)d_in[4];
  float* out = (float*)d_out;

  char* ws = (char*)d_ws;
  short* sbf  = (short*)(ws);                          // NB*SPAD bf16 = 25,165,824 B
  short* w1bf = (short*)(ws + 25165824);               // 256*1408*2 = 720,896 B
  short* w2bf = (short*)(ws + 25165824 + 720896);      // 1024*256*2 = 524,288 B

  hipLaunchKernelGGL(wconv1, dim3(1408), dim3(256), 0, stream, W1, w1bf);
  hipLaunchKernelGGL(wconv2, dim3(1024), dim3(256), 0, stream, W2, w2bf);
  hipLaunchKernelGGL(prep_summed, dim3(NB / 8), dim3(256), 0, stream, x, sbf);
  hipLaunchKernelGGL(gemm_fused, dim3(NB / 64), dim3(512), 0, stream,
                     x, sbf, w1bf, w2bf, b1, b2, out);
}

// Round 2
// 424.992 us; speedup vs baseline: 1.1193x; 1.1193x over previous
//
#include <hip/hip_runtime.h>
#include <stdint.h>
#include <stddef.h>

typedef __attribute__((ext_vector_type(8))) short short8;
typedef __attribute__((ext_vector_type(4))) float floatx4;

#define MFMA_BF16(A, B, C) __builtin_amdgcn_mfma_f32_16x16x32_bf16((A), (B), (C), 0, 0, 0)

static constexpr int NB   = 32768;
static constexpr int LV   = 1024;   // L, and folded K1
static constexpr int HIDV = 256;
static constexpr int OUTV = 1024;
static constexpr size_t HOFF = (size_t)NB * OUTV;  // d_out = [fund | h]

__device__ __forceinline__ short f2bf(float f) {
  union { float f; uint32_t u; } c; c.f = f;
  uint32_t u = c.u;
  u += 0x7fffu + ((u >> 16) & 1u);   // RNE to bf16
  return (short)(u >> 16);
}

// W1eff[n][k] = W1[n][k] + [k<341]*W1[n][1024+k] + [k<682]*0.5*W1[n][1024+k/2]
//            + [k<1023]*(1/3)*W1[n][1024+k/3]     (pooling folded into weights)
__global__ __launch_bounds__(256) void wconv1eff(const float* __restrict__ W1,
                                                 short* __restrict__ w1bf) {
  int idx = blockIdx.x * 256 + threadIdx.x;   // grid = 1024 -> 256*1024
  int n = idx >> 10;
  int k = idx & 1023;
  const float* r = W1 + (size_t)n * 1365;
  float v = r[k];
  if (k < 341)  v += r[1024 + k];
  if (k < 682)  v += 0.5f * r[1024 + (k >> 1)];
  if (k < 1023) v += (1.f / 3.f) * r[1024 + k / 3];
  w1bf[idx] = f2bf(v);
}

__global__ __launch_bounds__(256) void wconv2(const float* __restrict__ W2,
                                              short* __restrict__ w2bf) {
  int idx = blockIdx.x * 256 + threadIdx.x;   // grid = 1024
  w2bf[idx] = f2bf(W2[idx]);
}

// Fused: h-copy + GEMM1(relu, K=1024) + GEMM2(K=256), M-tile=64, 8 waves.
// GEMM1: wave owns 32 of 256 hid cols. GEMM2: 4 sequential N-quarters,
// wave owns 32 of 256 cols per quarter (keeps live acc at 32 VGPRs).
__global__ __launch_bounds__(512, 4) void gemm_fused(
    const float* __restrict__ x,
    const short* __restrict__ w1bf, const short* __restrict__ w2bf,
    const float* __restrict__ b1, const float* __restrict__ b2,
    float* __restrict__ out) {
  // row stride 72 shorts (144 B): /16B = 9 (odd) -> balanced bank groups for b128
  __shared__ __align__(16) short Abuf[2][64 * 72];
  // row stride 264 shorts (528 B): /16B = 33 (odd) -> balanced
  __shared__ __align__(16) short Hbuf[64 * 264];

  const int tid  = threadIdx.x;
  const int wave = tid >> 6;
  const int lane = tid & 63;
  const int l15  = lane & 15;
  const int quad = lane >> 4;
  const int row0 = blockIdx.x * 64;

  const int srow = tid >> 3;   // staging row 0..63
  const int sseg = tid & 7;    // staging segment 0..7 (8 fp32 each)

  float4 xa, xb;
  const floatx4 fzero = {0.f, 0.f, 0.f, 0.f};

  const float4* xrow = reinterpret_cast<const float4*>(x + (size_t)(row0 + srow) * LV);
  float4* hrow = reinterpret_cast<float4*>(out + HOFF + (size_t)(row0 + srow) * LV);

  auto loadA = [&](int ck) {
    xa = xrow[ck * 16 + 2 * sseg];
    xb = xrow[ck * 16 + 2 * sseg + 1];
  };
  auto writeA = [&](int buf, int ck) {
    short8 p;
    p[0] = f2bf(xa.x); p[1] = f2bf(xa.y); p[2] = f2bf(xa.z); p[3] = f2bf(xa.w);
    p[4] = f2bf(xb.x); p[5] = f2bf(xb.y); p[6] = f2bf(xb.z); p[7] = f2bf(xb.w);
    *reinterpret_cast<short8*>(&Abuf[buf][srow * 72 + sseg * 8]) = p;
    hrow[ck * 16 + 2 * sseg]     = xa;   // fused h-copy: x staged exactly once
    hrow[ck * 16 + 2 * sseg + 1] = xb;
  };

  short8 Breg[4], Bnxt[4];   // [ks*2+ns]
  auto loadB1 = [&](int ck, short8* dst) {
    #pragma unroll
    for (int ks = 0; ks < 2; ++ks)
      #pragma unroll
      for (int ns = 0; ns < 2; ++ns)
        dst[ks * 2 + ns] = *reinterpret_cast<const short8*>(
            w1bf + (size_t)(wave * 32 + ns * 16 + l15) * LV + ck * 64 + ks * 32 + quad * 8);
  };

  floatx4 acc1[4][2];
  #pragma unroll
  for (int ms = 0; ms < 4; ++ms)
    #pragma unroll
    for (int ns = 0; ns < 2; ++ns)
      acc1[ms][ns] = fzero;

  loadA(0);
  loadB1(0, Breg);

  #pragma unroll 1
  for (int ck = 0; ck < 16; ++ck) {
    const int buf = ck & 1;
    writeA(buf, ck);
    if (ck < 15) { loadA(ck + 1); loadB1(ck + 1, Bnxt); }
    __syncthreads();
    #pragma unroll
    for (int ks = 0; ks < 2; ++ks) {
      short8 afr[4];
      #pragma unroll
      for (int ms = 0; ms < 4; ++ms)
        afr[ms] = *reinterpret_cast<const short8*>(
            &Abuf[buf][(ms * 16 + l15) * 72 + ks * 32 + quad * 8]);
      #pragma unroll
      for (int ms = 0; ms < 4; ++ms)
        #pragma unroll
        for (int ns = 0; ns < 2; ++ns)
          acc1[ms][ns] = MFMA_BF16(afr[ms], Breg[ks * 2 + ns], acc1[ms][ns]);
    }
    #pragma unroll
    for (int i = 0; i < 4; ++i) Breg[i] = Bnxt[i];
  }

  // GEMM1 epilogue: bias + relu -> bf16 Hbuf (C-layout: row = quad*4+r, col = l15)
  #pragma unroll
  for (int ms = 0; ms < 4; ++ms) {
    #pragma unroll
    for (int ns = 0; ns < 2; ++ns) {
      const int n = wave * 32 + ns * 16 + l15;
      const float bias = b1[n];
      #pragma unroll
      for (int r = 0; r < 4; ++r) {
        const int m = ms * 16 + quad * 4 + r;
        float v = acc1[ms][ns][r] + bias;
        Hbuf[m * 264 + n] = f2bf(v > 0.f ? v : 0.f);
      }
    }
  }
  __syncthreads();

  // GEMM2: K=256 from Hbuf, 4 sequential N-quarters of 256
  short8 B2[2], B2n[2];
  auto loadB2 = [&](int q, int kc, short8* dst) {
    #pragma unroll
    for (int ns = 0; ns < 2; ++ns)
      dst[ns] = *reinterpret_cast<const short8*>(
          w2bf + (size_t)(q * 256 + wave * 32 + ns * 16 + l15) * HIDV + kc * 32 + quad * 8);
  };

  #pragma unroll 1
  for (int q = 0; q < 4; ++q) {
    floatx4 acc2[4][2];
    #pragma unroll
    for (int ms = 0; ms < 4; ++ms)
      #pragma unroll
      for (int ns = 0; ns < 2; ++ns)
        acc2[ms][ns] = fzero;
    loadB2(q, 0, B2);
    #pragma unroll 1
    for (int kc = 0; kc < 8; ++kc) {
      short8 afr[4];
      #pragma unroll
      for (int ms = 0; ms < 4; ++ms)
        afr[ms] = *reinterpret_cast<const short8*>(
            &Hbuf[(ms * 16 + l15) * 264 + kc * 32 + quad * 8]);
      if (kc < 7) loadB2(q, kc + 1, B2n);
      #pragma unroll
      for (int ms = 0; ms < 4; ++ms)
        #pragma unroll
        for (int ns = 0; ns < 2; ++ns)
          acc2[ms][ns] = MFMA_BF16(afr[ms], B2[ns], acc2[ms][ns]);
      #pragma unroll
      for (int i = 0; i < 2; ++i) B2[i] = B2n[i];
    }
    #pragma unroll
    for (int ms = 0; ms < 4; ++ms) {
      #pragma unroll
      for (int ns = 0; ns < 2; ++ns) {
        const int o = q * 256 + wave * 32 + ns * 16 + l15;
        const float bias = b2[o];
        #pragma unroll
        for (int r = 0; r < 4; ++r) {
          const int m = ms * 16 + quad * 4 + r;
          out[(size_t)(row0 + m) * OUTV + o] = acc2[ms][ns][r] + bias;
        }
      }
    }
  }
}

extern "C" void kernel_launch(void* const* d_in, const int* in_sizes, int n_in,
                              void* d_out, int out_size, void* d_ws, size_t ws_size,
                              hipStream_t stream) {
  const float* x  = (const float*)d_in[0];
  const float* W1 = (const float*)d_in[1];
  const float* b1 = (const float*)d_in[2];
  const float* W2 = (const float*)d_in[3];
  const float* b2 = (const float*)d_in[4];
  float* out = (float*)d_out;

  char* ws = (char*)d_ws;
  short* w1bf = (short*)(ws);                // 256*1024*2  = 524,288 B
  short* w2bf = (short*)(ws + 524288);       // 1024*256*2  = 524,288 B

  hipLaunchKernelGGL(wconv1eff, dim3(1024), dim3(256), 0, stream, W1, w1bf);
  hipLaunchKernelGGL(wconv2,    dim3(1024), dim3(256), 0, stream, W2, w2bf);
  hipLaunchKernelGGL(gemm_fused, dim3(NB / 64), dim3(512), 0, stream,
                     x, w1bf, w2bf, b1, b2, out);
}